// Round 23
// baseline (104.533 us; speedup 1.0000x reference)
//
#include <hip/hip_runtime.h>
#include <hip/hip_bf16.h>

// GRIN MoE feed-forward, routed top-2, bf16 MFMA grouped GEMM.
// T=4096 tokens, H=512, F=1024, E=8.
// R1 counting-sort routing. R2 gload_lds. R7 fused pre. R9 expert-contiguous
// XCD map. R12 fused memset. R17 K-panel-major weights+hbuf. R19 bounds fix +
// build||transconv. R20 gemm2 576-block geometry. R22 pre rebalance (101.4us).
// R23: gemm1 -> 2-buffer 2-phase drain-0, 48KB LDS, 3 blk/CU -> 576 blocks in
//      ONE round (was 72KB/2 blk/CU: 512+64 two-round, 2nd round 12% util).
//      R16's spill trap avoided: launch_bounds stays (512,4); R21 showed
//      drain-0 ~= counted-vmcnt per block in this regime.

#define T_TOK 4096
#define HDIM  512
#define FDIM  1024
#define NEXP  8
#define MAXT1 72
#define SLOTP 8320

typedef __attribute__((ext_vector_type(8))) __bf16 bf16x8;
typedef __attribute__((ext_vector_type(4))) float  f32x4;
typedef unsigned short ushort_t;

__device__ __forceinline__ unsigned int f2bf(float f) {
  __hip_bfloat16 h = __float2bfloat16(f);
  return (unsigned int)__builtin_bit_cast(unsigned short, h);
}

__device__ __forceinline__ void gload16(const ushort_t* g, ushort_t* l) {
  __builtin_amdgcn_global_load_lds(
      (const __attribute__((address_space(1))) unsigned int*)g,
      (__attribute__((address_space(3))) unsigned int*)l, 16, 0, 0);
}

// ---- shared transconv body: unit b in [0,12288) ----------------------------
__device__ __forceinline__ void transconv_unit(
    int b, const float* __restrict__ w1, const float* __restrict__ w3,
    const float* __restrict__ w2, ushort_t* __restrict__ w1p,
    ushort_t* __restrict__ w3p, ushort_t* __restrict__ w2p, float (*tile)[33]) {
  const float* src; ushort_t* dst; int R, C, rt, ct, e;
  if (b < 8192) {
    src = (b < 4096) ? w1 : w3; dst = (b < 4096) ? w1p : w3p;
    int r = b & 4095; e = r >> 9; r &= 511;
    R = HDIM; C = FDIM; rt = r >> 5; ct = r & 31;
  } else {
    src = w2; dst = w2p;
    int r = b - 8192; e = r >> 9; r &= 511;
    R = FDIM; C = HDIM; rt = r >> 4; ct = r & 15;
  }
  int rb = rt * 32, cb = ct * 32;
  int tr = threadIdx.x >> 3, tc = (threadIdx.x & 7) * 4;
  const float* s = src + ((size_t)e * R + rb + tr) * C + cb + tc;
  float4 v = *reinterpret_cast<const float4*>(s);
  tile[tc + 0][tr] = v.x; tile[tc + 1][tr] = v.y;
  tile[tc + 2][tr] = v.z; tile[tc + 3][tr] = v.w;
  __syncthreads();
  ushort4 ov = {(ushort_t)f2bf(tile[tr][tc]), (ushort_t)f2bf(tile[tr][tc + 1]),
                (ushort_t)f2bf(tile[tr][tc + 2]), (ushort_t)f2bf(tile[tr][tc + 3])};
  size_t da = (((size_t)e * (R >> 5) + (rb >> 5)) * C + cb + tr) * 32 + tc;
  *reinterpret_cast<ushort4*>(dst + da) = ov;
}

// --- preA: gating (0..1023) + transconv units 0..6143 ------------------------
__global__ void preA_kernel(const float* __restrict__ x, const float* __restrict__ wg,
                            const float* __restrict__ bg, int4* __restrict__ selraw,
                            ushort_t* __restrict__ xbuf,
                            const float* __restrict__ w1, const float* __restrict__ w3,
                            const float* __restrict__ w2, ushort_t* __restrict__ w1p,
                            ushort_t* __restrict__ w3p, ushort_t* __restrict__ w2p) {
  __shared__ float tile[32][33];
  int blk = blockIdx.x;
  if (blk < 1024) {
    int wv = threadIdx.x >> 6;
    int lane = threadIdx.x & 63;
    int t = blk * 4 + wv;
    const float* xr = x + (size_t)t * HDIM + lane * 8;
    float4 xa = *reinterpret_cast<const float4*>(xr);
    float4 xb = *reinterpret_cast<const float4*>(xr + 4);
    uint4 o;
    o.x = f2bf(xa.x) | (f2bf(xa.y) << 16);
    o.y = f2bf(xa.z) | (f2bf(xa.w) << 16);
    o.z = f2bf(xb.x) | (f2bf(xb.y) << 16);
    o.w = f2bf(xb.z) | (f2bf(xb.w) << 16);
    *reinterpret_cast<uint4*>(xbuf + (size_t)t * HDIM + lane * 8) = o;

    float xv[8] = {xa.x, xa.y, xa.z, xa.w, xb.x, xb.y, xb.z, xb.w};
    float acc[8];
#pragma unroll
    for (int e = 0; e < 8; e++) acc[e] = 0.f;
    int h0 = lane * 8;
#pragma unroll
    for (int j = 0; j < 8; j++) {
      const float4* wr = reinterpret_cast<const float4*>(wg + (size_t)(h0 + j) * 8);
      float4 w0 = wr[0], w1v = wr[1];
      float xj = xv[j];
      acc[0] += xj * w0.x; acc[1] += xj * w0.y; acc[2] += xj * w0.z; acc[3] += xj * w0.w;
      acc[4] += xj * w1v.x; acc[5] += xj * w1v.y; acc[6] += xj * w1v.z; acc[7] += xj * w1v.w;
    }
#pragma unroll
    for (int s = 32; s >= 1; s >>= 1) {
#pragma unroll
      for (int e = 0; e < 8; e++) acc[e] += __shfl_xor(acc[e], s, 64);
    }
    if (lane == 0) {
      float sc[8];
      float mx = -1e30f;
      for (int e = 0; e < 8; e++) { sc[e] = acc[e] + bg[e]; mx = fmaxf(mx, sc[e]); }
      float sum = 0.f;
      for (int e = 0; e < 8; e++) { sc[e] = expf(sc[e] - mx); sum += sc[e]; }
      for (int e = 0; e < 8; e++) sc[e] /= sum;
      int s1 = 0; float mx1 = sc[0];
      for (int e = 1; e < 8; e++) if (sc[e] > mx1) { mx1 = sc[e]; s1 = e; }
      float den1 = 0.f;
      for (int e = 0; e < 8; e++)
        if (!((mx1 - sc[e]) / mx1 > 0.02f)) den1 += expf(sc[e] - mx1);
      float mult1 = 1.0f / den1;
      int s2 = 0; float mx2 = -1e30f;
      for (int e = 0; e < 8; e++) if (e != s1 && sc[e] > mx2) { mx2 = sc[e]; s2 = e; }
      float den2 = 0.f;
      for (int e = 0; e < 8; e++) {
        if (e == s1) continue;
        float fac = fmaxf(sc[e], mx2);
        if (!((mx2 - sc[e]) / fac > 0.02f)) den2 += expf(sc[e] - mx2);
      }
      float mult2 = 1.0f / den2;
      selraw[t] = make_int4(s1, s2, __float_as_int(mult1), __float_as_int(mult2));
    }
    return;
  }
  transconv_unit(blk - 1024, w1, w3, w2, w1p, w3p, w2p, tile);
}

// --- preB: build (block 0) + transconv units 6144..12287 + zero-out ----------
__global__ __launch_bounds__(256) void preB_kernel(
    const int4* __restrict__ selraw, int* __restrict__ cnt, int* __restrict__ offs,
    int2* __restrict__ sched1, int* __restrict__ slot2tok, float* __restrict__ wtls,
    const float* __restrict__ w1, const float* __restrict__ w3,
    const float* __restrict__ w2, ushort_t* __restrict__ w1p,
    ushort_t* __restrict__ w3p, ushort_t* __restrict__ w2p,
    float* __restrict__ outz) {
  if (blockIdx.x > 6144) {
    int i = ((int)blockIdx.x - 6145) * 1024 + threadIdx.x * 4;
    *reinterpret_cast<float4*>(outz + i) = make_float4(0.f, 0.f, 0.f, 0.f);
    return;
  }
  if (blockIdx.x != 0) {
    __shared__ float tile[32][33];
    transconv_unit(6143 + blockIdx.x, w1, w3, w2, w1p, w3p, w2p, tile);
    return;
  }
  __shared__ int scan[256][8];
  __shared__ int loc[256][8];
  __shared__ int offs_sh[8];
  int tid = threadIdx.x;
#pragma unroll
  for (int e = 0; e < 8; e++) { scan[tid][e] = 0; loc[tid][e] = 0; }
  int t0 = tid * (T_TOK / 256);
  int4 raw[T_TOK / 256];
#pragma unroll
  for (int i = 0; i < T_TOK / 256; i++) {
    raw[i] = selraw[t0 + i];
    loc[tid][raw[i].x]++;
    loc[tid][raw[i].y]++;
  }
#pragma unroll
  for (int e = 0; e < 8; e++) scan[tid][e] = loc[tid][e];
  __syncthreads();
  for (int s = 1; s < 256; s <<= 1) {
    int v[8];
    if (tid >= s) {
#pragma unroll
      for (int e = 0; e < 8; e++) v[e] = scan[tid - s][e];
    }
    __syncthreads();
    if (tid >= s) {
#pragma unroll
      for (int e = 0; e < 8; e++) scan[tid][e] += v[e];
    }
    __syncthreads();
  }
  if (tid == 0) {
    int a = 0, t1 = 0;
    for (int e = 0; e < 8; e++) {
      int ce = scan[255][e];
      cnt[e] = ce; offs[e] = a; offs_sh[e] = a; a += ce;
    }
    for (int e = 0; e < 8; e++)
      for (int b = 0; b < scan[255][e]; b += 128) sched1[t1++] = make_int2(e, b);
    for (; t1 < MAXT1; t1++) sched1[t1] = make_int2(-1, 0);
  }
#pragma unroll
  for (int e = 0; e < 8; e++) scan[tid][e] -= loc[tid][e];
  __syncthreads();
#pragma unroll
  for (int i = 0; i < T_TOK / 256; i++) {
    int t = t0 + i;
    int s1 = raw[i].x, s2 = raw[i].y;
    int p1 = scan[tid][s1]++;
    int sl1 = offs_sh[s1] + p1;
    slot2tok[sl1] = t; wtls[sl1] = __int_as_float(raw[i].z);
    int p2 = scan[tid][s2]++;
    int sl2 = offs_sh[s2] + p2;
    slot2tok[sl2] = t; wtls[sl2] = __int_as_float(raw[i].w);
  }
}

// ---------------- GEMM1: h = gelu(x@w1) * (x@w3) * wt ------------------------
// Tile 128M x 128N x BK32, 8 waves (2Mx4N, wave = 64Mx32N). 512 threads.
// X token-major (gathered via toks); W1/W3 K-panel-major (contiguous 1KB/wave).
// 2-buffer 2-phase drain-0: {vmcnt(0); barrier; STAGE(next); compute(cur)}.
// 48 KB LDS -> 3 blocks/CU -> 576 blocks in ONE round. hbuf K-panel-major.
#define STAGE1(b, kc) do { \
    gload16(gx + (kc) * 32, &Xs[b][(wv * 64 + lane) * 8]); \
    gload16(gw1 + (size_t)(kc) * (FDIM * 32), &W1s[b][(wv * 64 + lane) * 8]); \
    gload16(gw3 + (size_t)(kc) * (FDIM * 32), &W3s[b][(wv * 64 + lane) * 8]); \
  } while (0)

__global__ __launch_bounds__(512, 4) void gemm1_kernel(
    const ushort_t* __restrict__ xb, const ushort_t* __restrict__ w1p,
    const ushort_t* __restrict__ w3p, const int* __restrict__ slot2tok,
    const float* __restrict__ wtls, const int* __restrict__ cnt,
    const int* __restrict__ offs, const int2* __restrict__ sched,
    ushort_t* __restrict__ hbufp) {
  int bid = blockIdx.x;
  int xcd = bid & 7, j = bid >> 3;        // j in 0..71
  int mt = xcd * 9 + (j >> 3);
  int nb = j & 7;
  int2 sc = sched[mt];
  if (sc.x < 0) return;
  int e = sc.x, base = sc.y;
  int cnte = cnt[e], off0 = offs[e];
  int rows = min(128, cnte - base);
  int sb = off0 + base;
  int n0 = nb * 128;
  __shared__ ushort_t Xs[2][4096];
  __shared__ ushort_t W1s[2][4096];
  __shared__ ushort_t W3s[2][4096];
  __shared__ int toks[128];
  __shared__ float wtl_sh[128];
  int tid = threadIdx.x;
  if (tid < 128) {
    toks[tid] = slot2tok[sb + min(tid, rows - 1)];
    wtl_sh[tid] = (tid < rows) ? wtls[sb + tid] : 0.f;
  }
  int lane = tid & 63, wv = tid >> 6;     // wv 0..7
  int wm = (wv >> 2) * 64, wn = (wv & 3) * 32;
  __syncthreads();

  int rS = wv * 16 + (lane >> 2);
  int swz = ((lane & 3) ^ ((rS >> 1) & 3)) * 8;
  const ushort_t* gx  = xb + (size_t)toks[rS] * HDIM + swz;
  const ushort_t* gw1 = w1p + (((size_t)e * 16) * FDIM + n0 + rS) * 32 + swz;
  const ushort_t* gw3 = w3p + (((size_t)e * 16) * FDIM + n0 + rS) * 32 + swz;

  f32x4 accU[4][2], accV[4][2];
#pragma unroll
  for (int m = 0; m < 4; m++)
#pragma unroll
    for (int n = 0; n < 2; n++) {
      accU[m][n] = {0.f, 0.f, 0.f, 0.f};
      accV[m][n] = {0.f, 0.f, 0.f, 0.f};
    }

  STAGE1(0, 0);

  int uc = lane >> 4;  // 0..3
#pragma unroll
  for (int t = 0; t < 16; t++) {
    const int cur = t & 1;
    asm volatile("s_waitcnt vmcnt(0)" ::: "memory");
    __builtin_amdgcn_s_barrier();
    __builtin_amdgcn_sched_barrier(0);
    if (t < 15) STAGE1(cur ^ 1, t + 1);
    bf16x8 a[4], bu[2], bv[2];
#pragma unroll
    for (int m = 0; m < 4; m++) {
      int r = wm + m * 16 + (lane & 15);
      a[m] = __builtin_bit_cast(bf16x8,
          *reinterpret_cast<const uint4*>(&Xs[cur][(r * 4 + (uc ^ ((r >> 1) & 3))) * 8]));
    }
#pragma unroll
    for (int n = 0; n < 2; n++) {
      int r = wn + n * 16 + (lane & 15);
      bu[n] = __builtin_bit_cast(bf16x8,
          *reinterpret_cast<const uint4*>(&W1s[cur][(r * 4 + (uc ^ ((r >> 1) & 3))) * 8]));
      bv[n] = __builtin_bit_cast(bf16x8,
          *reinterpret_cast<const uint4*>(&W3s[cur][(r * 4 + (uc ^ ((r >> 1) & 3))) * 8]));
    }
#pragma unroll
    for (int m = 0; m < 4; m++)
#pragma unroll
      for (int n = 0; n < 2; n++) {
        accU[m][n] = __builtin_amdgcn_mfma_f32_16x16x32_bf16(a[m], bu[n], accU[m][n], 0, 0, 0);
        accV[m][n] = __builtin_amdgcn_mfma_f32_16x16x32_bf16(a[m], bv[n], accV[m][n], 0, 0, 0);
      }
  }

#pragma unroll
  for (int m = 0; m < 4; m++) {
#pragma unroll
    for (int rr = 0; rr < 4; rr++) {
      int row = wm + m * 16 + ((lane >> 4) << 2) + rr;
      if (row < rows) {
        float wgt = wtl_sh[row];
        int slot = sb + row;
#pragma unroll
        for (int n = 0; n < 2; n++) {
          int f = n0 + wn + n * 16 + (lane & 15);
          float u = accU[m][n][rr], v = accV[m][n][rr];
          float h = 0.5f * u * (1.0f + erff(u * 0.707106781186547524f)) * v * wgt;
          hbufp[((size_t)(f >> 5) * SLOTP + slot) * 32 + (f & 31)] = (ushort_t)f2bf(h);
        }
      }
    }
  }
}

// ---------------- GEMM2: out[tok] += h @ w2  (contiguous slots) --------------
// Tile 128M x 64N x BK32, 4 waves (2Mx2N, wave = 64Mx32N). 256 threads.
// 576 blocks (single round, 4 blk/CU capacity). K-panel-major operands,
// 3-buffer counted vmcnt(3), 36 KB LDS. fp32 atomicAdd epilogue.
#define STAGE2(b, kc) do { \
    gload16(ga0 + (size_t)(kc) * (SLOTP * 32), &As[b][(wv * 2 + 0) * 512 + lane * 8]); \
    gload16(ga1 + (size_t)(kc) * (SLOTP * 32), &As[b][(wv * 2 + 1) * 512 + lane * 8]); \
    gload16(gb0 + (size_t)(kc) * (HDIM * 32),  &Bs[b][(wv * 64 + lane) * 8]); \
  } while (0)

__global__ __launch_bounds__(256, 4) void gemm2_kernel(
    const ushort_t* __restrict__ hbufp, const ushort_t* __restrict__ w2p,
    const int* __restrict__ slot2tok, const int* __restrict__ cnt,
    const int* __restrict__ offs, const int2* __restrict__ sched,
    float* __restrict__ out) {
  int bid = blockIdx.x;
  int xcd = bid & 7, j = bid >> 3;        // j in 0..71
  int mt = xcd * 9 + (j >> 3);
  int nb = j & 7;
  int2 sc = sched[mt];
  if (sc.x < 0) return;
  int e = sc.x, base = sc.y;
  int cnte = cnt[e], off0 = offs[e];
  int rows = min(128, cnte - base);
  int sb = off0 + base;
  int n0 = nb * 64;
  __shared__ ushort_t As[3][4096];   // 128 rows x 32 k (8 KB/buf)
  __shared__ ushort_t Bs[3][2048];   // 64 n-rows x 32 k (4 KB/buf)
  __shared__ int toks[128];
  int tid = threadIdx.x;
  if (tid < 128) toks[tid] = slot2tok[sb + min(tid, rows - 1)];
  int lane = tid & 63, wv = tid >> 6;     // wv 0..3
  int wm = (wv >> 1) * 64, wn = (wv & 1) * 32;
  __syncthreads();

  int rA0 = wv * 32 + (lane >> 2);
  int rB  = wv * 16 + (lane >> 2);
  int swz = ((lane & 3) ^ ((lane >> 3) & 3)) * 8;
  const ushort_t* ga0 = hbufp + ((size_t)(sb + rA0)) * 32 + swz;
  const ushort_t* ga1 = hbufp + ((size_t)(sb + rA0 + 16)) * 32 + swz;
  const ushort_t* gb0 = w2p + (((size_t)e * 32) * HDIM + n0 + rB) * 32 + swz;

  f32x4 acc[4][2];
#pragma unroll
  for (int m = 0; m < 4; m++)
#pragma unroll
    for (int n = 0; n < 2; n++) acc[m][n] = {0.f, 0.f, 0.f, 0.f};

  STAGE2(0, 0);
  STAGE2(1, 1);

  int uc = lane >> 4;  // 0..3
#pragma unroll
  for (int t = 0; t < 32; t++) {
    if (t < 31) asm volatile("s_waitcnt vmcnt(3)" ::: "memory");
    else        asm volatile("s_waitcnt vmcnt(0)" ::: "memory");
    __builtin_amdgcn_s_barrier();
    __builtin_amdgcn_sched_barrier(0);
    if (t < 30) STAGE2((t + 2) % 3, t + 2);
    const int cur = t % 3;
    bf16x8 a[4], b[2];
#pragma unroll
    for (int m = 0; m < 4; m++) {
      int r = wm + m * 16 + (lane & 15);
      a[m] = __builtin_bit_cast(bf16x8,
          *reinterpret_cast<const uint4*>(&As[cur][(r * 4 + (uc ^ ((r >> 1) & 3))) * 8]));
    }
#pragma unroll
    for (int n = 0; n < 2; n++) {
      int r = wn + n * 16 + (lane & 15);
      b[n] = __builtin_bit_cast(bf16x8,
          *reinterpret_cast<const uint4*>(&Bs[cur][(r * 4 + (uc ^ ((r >> 1) & 3))) * 8]));
    }
#pragma unroll
    for (int m = 0; m < 4; m++)
#pragma unroll
      for (int n = 0; n < 2; n++)
        acc[m][n] = __builtin_amdgcn_mfma_f32_16x16x32_bf16(a[m], b[n], acc[m][n], 0, 0, 0);
  }

#pragma unroll
  for (int m = 0; m < 4; m++) {
#pragma unroll
    for (int rr = 0; rr < 4; rr++) {
      int row = wm + m * 16 + ((lane >> 4) << 2) + rr;
      if (row < rows) {
        int tok = toks[row];
        float* po = out + (size_t)tok * HDIM + n0 + wn + (lane & 15);
#pragma unroll
        for (int n = 0; n < 2; n++) atomicAdd(po + n * 16, acc[m][n][rr]);
      }
    }
  }
}

// ---------------- launch ----------------------------------------------------
extern "C" void kernel_launch(void* const* d_in, const int* in_sizes, int n_in,
                              void* d_out, int out_size, void* d_ws, size_t ws_size,
                              hipStream_t stream) {
  const float* x  = (const float*)d_in[0];
  const float* wg = (const float*)d_in[1];
  const float* bg = (const float*)d_in[2];
  const float* w1 = (const float*)d_in[3];
  const float* w3 = (const float*)d_in[4];
  const float* w2 = (const float*)d_in[5];
  float* out = (float*)d_out;
  char* ws = (char*)d_ws;

  int*   cnt     = (int*)(ws + 0);
  int*   offs    = (int*)(ws + 64);
  int2*  sched1  = (int2*)(ws + 128);                 // 576 B
  int4*  selraw  = (int4*)(ws + 65536);               // 64 KB
  int*   slot2tok= (int*)(ws + 131072);               // 33 KB
  float* wtls    = (float*)(ws + 262144);             // 33 KB
  ushort_t* xb    = (ushort_t*)(ws + (1ull << 20));   // 4 MB
  ushort_t* w1p   = (ushort_t*)(ws + (14ull << 20));  // 8 MB
  ushort_t* w3p   = (ushort_t*)(ws + (22ull << 20));  // 8 MB
  ushort_t* w2p   = (ushort_t*)(ws + (30ull << 20));  // 8 MB
  ushort_t* hbufp = (ushort_t*)(ws + (38ull << 20));  // 17.04 MB [32][8320][32]

  preA_kernel<<<1024 + 6144, 256, 0, stream>>>(x, wg, bg, selraw, xb,
                                               w1, w3, w2, w1p, w3p, w2p);
  preB_kernel<<<1 + 6144 + 2048, 256, 0, stream>>>(selraw, cnt, offs, sched1,
                                                   slot2tok, wtls,
                                                   w1, w3, w2, w1p, w3p, w2p, out);
  gemm1_kernel<<<8 * MAXT1, 512, 0, stream>>>(xb, w1p, w3p, slot2tok, wtls, cnt,
                                              offs, sched1, hbufp);
  gemm2_kernel<<<8 * MAXT1, 256, 0, stream>>>(hbufp, w2p, slot2tok, cnt, offs,
                                              sched1, out);
}

// Round 24
// 101.164 us; speedup vs baseline: 1.0333x; 1.0333x over previous
//
#include <hip/hip_runtime.h>
#include <hip/hip_bf16.h>

// GRIN MoE feed-forward, routed top-2, bf16 MFMA grouped GEMM.
// T=4096 tokens, H=512, F=1024, E=8.
// R1 counting-sort routing. R2 gload_lds. R7 fused pre. R9 expert-contiguous
// XCD map. R12 fused memset. R17 K-panel-major weights+hbuf. R19 bounds fix +
// build||transconv. R20 gemm2 576-block geometry. R22 pre rebalance (101.4us
// best). R23 (2-phase gemm1) regressed -> R24 restores R22 exactly.

#define T_TOK 4096
#define HDIM  512
#define FDIM  1024
#define NEXP  8
#define MAXT1 72
#define SLOTP 8320

typedef __attribute__((ext_vector_type(8))) __bf16 bf16x8;
typedef __attribute__((ext_vector_type(4))) float  f32x4;
typedef unsigned short ushort_t;

__device__ __forceinline__ unsigned int f2bf(float f) {
  __hip_bfloat16 h = __float2bfloat16(f);
  return (unsigned int)__builtin_bit_cast(unsigned short, h);
}

__device__ __forceinline__ void gload16(const ushort_t* g, ushort_t* l) {
  __builtin_amdgcn_global_load_lds(
      (const __attribute__((address_space(1))) unsigned int*)g,
      (__attribute__((address_space(3))) unsigned int*)l, 16, 0, 0);
}

// ---- shared transconv body: unit b in [0,12288) ----------------------------
__device__ __forceinline__ void transconv_unit(
    int b, const float* __restrict__ w1, const float* __restrict__ w3,
    const float* __restrict__ w2, ushort_t* __restrict__ w1p,
    ushort_t* __restrict__ w3p, ushort_t* __restrict__ w2p, float (*tile)[33]) {
  const float* src; ushort_t* dst; int R, C, rt, ct, e;
  if (b < 8192) {
    src = (b < 4096) ? w1 : w3; dst = (b < 4096) ? w1p : w3p;
    int r = b & 4095; e = r >> 9; r &= 511;
    R = HDIM; C = FDIM; rt = r >> 5; ct = r & 31;
  } else {
    src = w2; dst = w2p;
    int r = b - 8192; e = r >> 9; r &= 511;
    R = FDIM; C = HDIM; rt = r >> 4; ct = r & 15;
  }
  int rb = rt * 32, cb = ct * 32;
  int tr = threadIdx.x >> 3, tc = (threadIdx.x & 7) * 4;
  const float* s = src + ((size_t)e * R + rb + tr) * C + cb + tc;
  float4 v = *reinterpret_cast<const float4*>(s);
  tile[tc + 0][tr] = v.x; tile[tc + 1][tr] = v.y;
  tile[tc + 2][tr] = v.z; tile[tc + 3][tr] = v.w;
  __syncthreads();
  ushort4 ov = {(ushort_t)f2bf(tile[tr][tc]), (ushort_t)f2bf(tile[tr][tc + 1]),
                (ushort_t)f2bf(tile[tr][tc + 2]), (ushort_t)f2bf(tile[tr][tc + 3])};
  size_t da = (((size_t)e * (R >> 5) + (rb >> 5)) * C + cb + tr) * 32 + tc;
  *reinterpret_cast<ushort4*>(dst + da) = ov;
}

// --- preA: gating (0..1023) + transconv units 0..6143 ------------------------
__global__ void preA_kernel(const float* __restrict__ x, const float* __restrict__ wg,
                            const float* __restrict__ bg, int4* __restrict__ selraw,
                            ushort_t* __restrict__ xbuf,
                            const float* __restrict__ w1, const float* __restrict__ w3,
                            const float* __restrict__ w2, ushort_t* __restrict__ w1p,
                            ushort_t* __restrict__ w3p, ushort_t* __restrict__ w2p) {
  __shared__ float tile[32][33];
  int blk = blockIdx.x;
  if (blk < 1024) {
    int wv = threadIdx.x >> 6;
    int lane = threadIdx.x & 63;
    int t = blk * 4 + wv;
    const float* xr = x + (size_t)t * HDIM + lane * 8;
    float4 xa = *reinterpret_cast<const float4*>(xr);
    float4 xb = *reinterpret_cast<const float4*>(xr + 4);
    uint4 o;
    o.x = f2bf(xa.x) | (f2bf(xa.y) << 16);
    o.y = f2bf(xa.z) | (f2bf(xa.w) << 16);
    o.z = f2bf(xb.x) | (f2bf(xb.y) << 16);
    o.w = f2bf(xb.z) | (f2bf(xb.w) << 16);
    *reinterpret_cast<uint4*>(xbuf + (size_t)t * HDIM + lane * 8) = o;

    float xv[8] = {xa.x, xa.y, xa.z, xa.w, xb.x, xb.y, xb.z, xb.w};
    float acc[8];
#pragma unroll
    for (int e = 0; e < 8; e++) acc[e] = 0.f;
    int h0 = lane * 8;
#pragma unroll
    for (int j = 0; j < 8; j++) {
      const float4* wr = reinterpret_cast<const float4*>(wg + (size_t)(h0 + j) * 8);
      float4 w0 = wr[0], w1v = wr[1];
      float xj = xv[j];
      acc[0] += xj * w0.x; acc[1] += xj * w0.y; acc[2] += xj * w0.z; acc[3] += xj * w0.w;
      acc[4] += xj * w1v.x; acc[5] += xj * w1v.y; acc[6] += xj * w1v.z; acc[7] += xj * w1v.w;
    }
#pragma unroll
    for (int s = 32; s >= 1; s >>= 1) {
#pragma unroll
      for (int e = 0; e < 8; e++) acc[e] += __shfl_xor(acc[e], s, 64);
    }
    if (lane == 0) {
      float sc[8];
      float mx = -1e30f;
      for (int e = 0; e < 8; e++) { sc[e] = acc[e] + bg[e]; mx = fmaxf(mx, sc[e]); }
      float sum = 0.f;
      for (int e = 0; e < 8; e++) { sc[e] = expf(sc[e] - mx); sum += sc[e]; }
      for (int e = 0; e < 8; e++) sc[e] /= sum;
      int s1 = 0; float mx1 = sc[0];
      for (int e = 1; e < 8; e++) if (sc[e] > mx1) { mx1 = sc[e]; s1 = e; }
      float den1 = 0.f;
      for (int e = 0; e < 8; e++)
        if (!((mx1 - sc[e]) / mx1 > 0.02f)) den1 += expf(sc[e] - mx1);
      float mult1 = 1.0f / den1;
      int s2 = 0; float mx2 = -1e30f;
      for (int e = 0; e < 8; e++) if (e != s1 && sc[e] > mx2) { mx2 = sc[e]; s2 = e; }
      float den2 = 0.f;
      for (int e = 0; e < 8; e++) {
        if (e == s1) continue;
        float fac = fmaxf(sc[e], mx2);
        if (!((mx2 - sc[e]) / fac > 0.02f)) den2 += expf(sc[e] - mx2);
      }
      float mult2 = 1.0f / den2;
      selraw[t] = make_int4(s1, s2, __float_as_int(mult1), __float_as_int(mult2));
    }
    return;
  }
  transconv_unit(blk - 1024, w1, w3, w2, w1p, w3p, w2p, tile);
}

// --- preB: build (block 0) + transconv units 6144..12287 + zero-out ----------
__global__ __launch_bounds__(256) void preB_kernel(
    const int4* __restrict__ selraw, int* __restrict__ cnt, int* __restrict__ offs,
    int2* __restrict__ sched1, int* __restrict__ slot2tok, float* __restrict__ wtls,
    const float* __restrict__ w1, const float* __restrict__ w3,
    const float* __restrict__ w2, ushort_t* __restrict__ w1p,
    ushort_t* __restrict__ w3p, ushort_t* __restrict__ w2p,
    float* __restrict__ outz) {
  if (blockIdx.x > 6144) {
    int i = ((int)blockIdx.x - 6145) * 1024 + threadIdx.x * 4;
    *reinterpret_cast<float4*>(outz + i) = make_float4(0.f, 0.f, 0.f, 0.f);
    return;
  }
  if (blockIdx.x != 0) {
    __shared__ float tile[32][33];
    transconv_unit(6143 + blockIdx.x, w1, w3, w2, w1p, w3p, w2p, tile);
    return;
  }
  __shared__ int scan[256][8];
  __shared__ int loc[256][8];
  __shared__ int offs_sh[8];
  int tid = threadIdx.x;
#pragma unroll
  for (int e = 0; e < 8; e++) { scan[tid][e] = 0; loc[tid][e] = 0; }
  int t0 = tid * (T_TOK / 256);
  int4 raw[T_TOK / 256];
#pragma unroll
  for (int i = 0; i < T_TOK / 256; i++) {
    raw[i] = selraw[t0 + i];
    loc[tid][raw[i].x]++;
    loc[tid][raw[i].y]++;
  }
#pragma unroll
  for (int e = 0; e < 8; e++) scan[tid][e] = loc[tid][e];
  __syncthreads();
  for (int s = 1; s < 256; s <<= 1) {
    int v[8];
    if (tid >= s) {
#pragma unroll
      for (int e = 0; e < 8; e++) v[e] = scan[tid - s][e];
    }
    __syncthreads();
    if (tid >= s) {
#pragma unroll
      for (int e = 0; e < 8; e++) scan[tid][e] += v[e];
    }
    __syncthreads();
  }
  if (tid == 0) {
    int a = 0, t1 = 0;
    for (int e = 0; e < 8; e++) {
      int ce = scan[255][e];
      cnt[e] = ce; offs[e] = a; offs_sh[e] = a; a += ce;
    }
    for (int e = 0; e < 8; e++)
      for (int b = 0; b < scan[255][e]; b += 128) sched1[t1++] = make_int2(e, b);
    for (; t1 < MAXT1; t1++) sched1[t1] = make_int2(-1, 0);
  }
#pragma unroll
  for (int e = 0; e < 8; e++) scan[tid][e] -= loc[tid][e];
  __syncthreads();
#pragma unroll
  for (int i = 0; i < T_TOK / 256; i++) {
    int t = t0 + i;
    int s1 = raw[i].x, s2 = raw[i].y;
    int p1 = scan[tid][s1]++;
    int sl1 = offs_sh[s1] + p1;
    slot2tok[sl1] = t; wtls[sl1] = __int_as_float(raw[i].z);
    int p2 = scan[tid][s2]++;
    int sl2 = offs_sh[s2] + p2;
    slot2tok[sl2] = t; wtls[sl2] = __int_as_float(raw[i].w);
  }
}

// ---------------- GEMM1: h = gelu(x@w1) * (x@w3) * wt ------------------------
// Tile 128M x 128N x BK32, 8 waves (2Mx4N, wave = 64Mx32N). 512 threads.
// X token-major (gathered via toks); W1/W3 K-panel-major (contiguous 1KB/wave).
// 3-buffer counted-vmcnt pipeline, vmcnt(3). hbuf written K-panel-major.
#define STAGE1(b, kc) do { \
    gload16(gx + (kc) * 32, &Xs[b][(wv * 64 + lane) * 8]); \
    gload16(gw1 + (size_t)(kc) * (FDIM * 32), &W1s[b][(wv * 64 + lane) * 8]); \
    gload16(gw3 + (size_t)(kc) * (FDIM * 32), &W3s[b][(wv * 64 + lane) * 8]); \
  } while (0)

__global__ __launch_bounds__(512, 4) void gemm1_kernel(
    const ushort_t* __restrict__ xb, const ushort_t* __restrict__ w1p,
    const ushort_t* __restrict__ w3p, const int* __restrict__ slot2tok,
    const float* __restrict__ wtls, const int* __restrict__ cnt,
    const int* __restrict__ offs, const int2* __restrict__ sched,
    ushort_t* __restrict__ hbufp) {
  int bid = blockIdx.x;
  int xcd = bid & 7, j = bid >> 3;        // j in 0..71
  int mt = xcd * 9 + (j >> 3);
  int nb = j & 7;
  int2 sc = sched[mt];
  if (sc.x < 0) return;
  int e = sc.x, base = sc.y;
  int cnte = cnt[e], off0 = offs[e];
  int rows = min(128, cnte - base);
  int sb = off0 + base;
  int n0 = nb * 128;
  __shared__ ushort_t Xs[3][4096];
  __shared__ ushort_t W1s[3][4096];
  __shared__ ushort_t W3s[3][4096];
  __shared__ int toks[128];
  __shared__ float wtl_sh[128];
  int tid = threadIdx.x;
  if (tid < 128) {
    toks[tid] = slot2tok[sb + min(tid, rows - 1)];
    wtl_sh[tid] = (tid < rows) ? wtls[sb + tid] : 0.f;
  }
  int lane = tid & 63, wv = tid >> 6;     // wv 0..7
  int wm = (wv >> 2) * 64, wn = (wv & 3) * 32;
  __syncthreads();

  int rS = wv * 16 + (lane >> 2);
  int swz = ((lane & 3) ^ ((rS >> 1) & 3)) * 8;
  const ushort_t* gx  = xb + (size_t)toks[rS] * HDIM + swz;
  const ushort_t* gw1 = w1p + (((size_t)e * 16) * FDIM + n0 + rS) * 32 + swz;
  const ushort_t* gw3 = w3p + (((size_t)e * 16) * FDIM + n0 + rS) * 32 + swz;

  f32x4 accU[4][2], accV[4][2];
#pragma unroll
  for (int m = 0; m < 4; m++)
#pragma unroll
    for (int n = 0; n < 2; n++) {
      accU[m][n] = {0.f, 0.f, 0.f, 0.f};
      accV[m][n] = {0.f, 0.f, 0.f, 0.f};
    }

  STAGE1(0, 0);
  STAGE1(1, 1);

  int uc = lane >> 4;  // 0..3
#pragma unroll
  for (int t = 0; t < 16; t++) {
    if (t < 15) asm volatile("s_waitcnt vmcnt(3)" ::: "memory");
    else        asm volatile("s_waitcnt vmcnt(0)" ::: "memory");
    __builtin_amdgcn_s_barrier();
    __builtin_amdgcn_sched_barrier(0);
    if (t < 14) STAGE1((t + 2) % 3, t + 2);
    const int cur = t % 3;
    bf16x8 a[4], bu[2], bv[2];
#pragma unroll
    for (int m = 0; m < 4; m++) {
      int r = wm + m * 16 + (lane & 15);
      a[m] = __builtin_bit_cast(bf16x8,
          *reinterpret_cast<const uint4*>(&Xs[cur][(r * 4 + (uc ^ ((r >> 1) & 3))) * 8]));
    }
#pragma unroll
    for (int n = 0; n < 2; n++) {
      int r = wn + n * 16 + (lane & 15);
      bu[n] = __builtin_bit_cast(bf16x8,
          *reinterpret_cast<const uint4*>(&W1s[cur][(r * 4 + (uc ^ ((r >> 1) & 3))) * 8]));
      bv[n] = __builtin_bit_cast(bf16x8,
          *reinterpret_cast<const uint4*>(&W3s[cur][(r * 4 + (uc ^ ((r >> 1) & 3))) * 8]));
    }
#pragma unroll
    for (int m = 0; m < 4; m++)
#pragma unroll
      for (int n = 0; n < 2; n++) {
        accU[m][n] = __builtin_amdgcn_mfma_f32_16x16x32_bf16(a[m], bu[n], accU[m][n], 0, 0, 0);
        accV[m][n] = __builtin_amdgcn_mfma_f32_16x16x32_bf16(a[m], bv[n], accV[m][n], 0, 0, 0);
      }
  }

#pragma unroll
  for (int m = 0; m < 4; m++) {
#pragma unroll
    for (int rr = 0; rr < 4; rr++) {
      int row = wm + m * 16 + ((lane >> 4) << 2) + rr;
      if (row < rows) {
        float wgt = wtl_sh[row];
        int slot = sb + row;
#pragma unroll
        for (int n = 0; n < 2; n++) {
          int f = n0 + wn + n * 16 + (lane & 15);
          float u = accU[m][n][rr], v = accV[m][n][rr];
          float h = 0.5f * u * (1.0f + erff(u * 0.707106781186547524f)) * v * wgt;
          hbufp[((size_t)(f >> 5) * SLOTP + slot) * 32 + (f & 31)] = (ushort_t)f2bf(h);
        }
      }
    }
  }
}

// ---------------- GEMM2: out[tok] += h @ w2  (contiguous slots) --------------
// Tile 128M x 64N x BK32, 4 waves (2Mx2N, wave = 64Mx32N). 256 threads.
// 576 blocks (single round, 4 blk/CU capacity). K-panel-major operands,
// 3-buffer counted vmcnt(3), 36 KB LDS. fp32 atomicAdd epilogue.
#define STAGE2(b, kc) do { \
    gload16(ga0 + (size_t)(kc) * (SLOTP * 32), &As[b][(wv * 2 + 0) * 512 + lane * 8]); \
    gload16(ga1 + (size_t)(kc) * (SLOTP * 32), &As[b][(wv * 2 + 1) * 512 + lane * 8]); \
    gload16(gb0 + (size_t)(kc) * (HDIM * 32),  &Bs[b][(wv * 64 + lane) * 8]); \
  } while (0)

__global__ __launch_bounds__(256, 4) void gemm2_kernel(
    const ushort_t* __restrict__ hbufp, const ushort_t* __restrict__ w2p,
    const int* __restrict__ slot2tok, const int* __restrict__ cnt,
    const int* __restrict__ offs, const int2* __restrict__ sched,
    float* __restrict__ out) {
  int bid = blockIdx.x;
  int xcd = bid & 7, j = bid >> 3;        // j in 0..71
  int mt = xcd * 9 + (j >> 3);
  int nb = j & 7;
  int2 sc = sched[mt];
  if (sc.x < 0) return;
  int e = sc.x, base = sc.y;
  int cnte = cnt[e], off0 = offs[e];
  int rows = min(128, cnte - base);
  int sb = off0 + base;
  int n0 = nb * 64;
  __shared__ ushort_t As[3][4096];   // 128 rows x 32 k (8 KB/buf)
  __shared__ ushort_t Bs[3][2048];   // 64 n-rows x 32 k (4 KB/buf)
  __shared__ int toks[128];
  int tid = threadIdx.x;
  if (tid < 128) toks[tid] = slot2tok[sb + min(tid, rows - 1)];
  int lane = tid & 63, wv = tid >> 6;     // wv 0..3
  int wm = (wv >> 1) * 64, wn = (wv & 1) * 32;
  __syncthreads();

  int rA0 = wv * 32 + (lane >> 2);
  int rB  = wv * 16 + (lane >> 2);
  int swz = ((lane & 3) ^ ((lane >> 3) & 3)) * 8;
  const ushort_t* ga0 = hbufp + ((size_t)(sb + rA0)) * 32 + swz;
  const ushort_t* ga1 = hbufp + ((size_t)(sb + rA0 + 16)) * 32 + swz;
  const ushort_t* gb0 = w2p + (((size_t)e * 32) * HDIM + n0 + rB) * 32 + swz;

  f32x4 acc[4][2];
#pragma unroll
  for (int m = 0; m < 4; m++)
#pragma unroll
    for (int n = 0; n < 2; n++) acc[m][n] = {0.f, 0.f, 0.f, 0.f};

  STAGE2(0, 0);
  STAGE2(1, 1);

  int uc = lane >> 4;  // 0..3
#pragma unroll
  for (int t = 0; t < 32; t++) {
    if (t < 31) asm volatile("s_waitcnt vmcnt(3)" ::: "memory");
    else        asm volatile("s_waitcnt vmcnt(0)" ::: "memory");
    __builtin_amdgcn_s_barrier();
    __builtin_amdgcn_sched_barrier(0);
    if (t < 30) STAGE2((t + 2) % 3, t + 2);
    const int cur = t % 3;
    bf16x8 a[4], b[2];
#pragma unroll
    for (int m = 0; m < 4; m++) {
      int r = wm + m * 16 + (lane & 15);
      a[m] = __builtin_bit_cast(bf16x8,
          *reinterpret_cast<const uint4*>(&As[cur][(r * 4 + (uc ^ ((r >> 1) & 3))) * 8]));
    }
#pragma unroll
    for (int n = 0; n < 2; n++) {
      int r = wn + n * 16 + (lane & 15);
      b[n] = __builtin_bit_cast(bf16x8,
          *reinterpret_cast<const uint4*>(&Bs[cur][(r * 4 + (uc ^ ((r >> 1) & 3))) * 8]));
    }
#pragma unroll
    for (int m = 0; m < 4; m++)
#pragma unroll
      for (int n = 0; n < 2; n++)
        acc[m][n] = __builtin_amdgcn_mfma_f32_16x16x32_bf16(a[m], b[n], acc[m][n], 0, 0, 0);
  }

#pragma unroll
  for (int m = 0; m < 4; m++) {
#pragma unroll
    for (int rr = 0; rr < 4; rr++) {
      int row = wm + m * 16 + ((lane >> 4) << 2) + rr;
      if (row < rows) {
        int tok = toks[row];
        float* po = out + (size_t)tok * HDIM + n0 + wn + (lane & 15);
#pragma unroll
        for (int n = 0; n < 2; n++) atomicAdd(po + n * 16, acc[m][n][rr]);
      }
    }
  }
}

// ---------------- launch ----------------------------------------------------
extern "C" void kernel_launch(void* const* d_in, const int* in_sizes, int n_in,
                              void* d_out, int out_size, void* d_ws, size_t ws_size,
                              hipStream_t stream) {
  const float* x  = (const float*)d_in[0];
  const float* wg = (const float*)d_in[1];
  const float* bg = (const float*)d_in[2];
  const float* w1 = (const float*)d_in[3];
  const float* w3 = (const float*)d_in[4];
  const float* w2 = (const float*)d_in[5];
  float* out = (float*)d_out;
  char* ws = (char*)d_ws;

  int*   cnt     = (int*)(ws + 0);
  int*   offs    = (int*)(ws + 64);
  int2*  sched1  = (int2*)(ws + 128);                 // 576 B
  int4*  selraw  = (int4*)(ws + 65536);               // 64 KB
  int*   slot2tok= (int*)(ws + 131072);               // 33 KB
  float* wtls    = (float*)(ws + 262144);             // 33 KB
  ushort_t* xb    = (ushort_t*)(ws + (1ull << 20));   // 4 MB
  ushort_t* w1p   = (ushort_t*)(ws + (14ull << 20));  // 8 MB
  ushort_t* w3p   = (ushort_t*)(ws + (22ull << 20));  // 8 MB
  ushort_t* w2p   = (ushort_t*)(ws + (30ull << 20));  // 8 MB
  ushort_t* hbufp = (ushort_t*)(ws + (38ull << 20));  // 17.04 MB [32][8320][32]

  preA_kernel<<<1024 + 6144, 256, 0, stream>>>(x, wg, bg, selraw, xb,
                                               w1, w3, w2, w1p, w3p, w2p);
  preB_kernel<<<1 + 6144 + 2048, 256, 0, stream>>>(selraw, cnt, offs, sched1,
                                                   slot2tok, wtls,
                                                   w1, w3, w2, w1p, w3p, w2p, out);
  gemm1_kernel<<<8 * MAXT1, 512, 0, stream>>>(xb, w1p, w3p, slot2tok, wtls, cnt,
                                              offs, sched1, hbufp);
  gemm2_kernel<<<8 * MAXT1, 256, 0, stream>>>(hbufp, w2p, slot2tok, cnt, offs,
                                              sched1, out);
}